// Round 2
// baseline (148496.985 us; speedup 1.0000x reference)
//
#include <hip/hip_runtime.h>
#include <stdint.h>
#include <math.h>

#define T_STEPS 1000

typedef __attribute__((ext_vector_type(4))) float f32x4;
typedef __attribute__((ext_vector_type(8))) short bf16x8;

__device__ __forceinline__ unsigned short f2bf(float f) {
    union { float f; unsigned u; } v; v.f = f;
    return (unsigned short)((v.u + 0x7FFFu + ((v.u >> 16) & 1u)) >> 16);
}
__device__ __forceinline__ float bf2f(unsigned short b) {
    union { unsigned u; float f; } v; v.u = ((unsigned)b) << 16;
    return v.f;
}
// split fp32 -> 3 bf16 limbs (exact to 2^-24 relative)
__device__ __forceinline__ void split3(float v, unsigned short& h, unsigned short& m, unsigned short& l) {
    h = f2bf(v);
    float r1 = v - bf2f(h);
    m = f2bf(r1);
    float r2 = r1 - bf2f(m);
    l = f2bf(r2);
}

// ---------------- coefficients: fp32 cumprod to match np.cumprod exactly ----------------
__global__ void scalars_kernel(float* As, float* Bc, float* Dc) {
    if (threadIdx.x == 0 && blockIdx.x == 0) {
        float acp = 1.0f;
        float ac_prev = 1.0f;
        for (int t = 0; t < T_STEPS; ++t) {
            float beta = (float)(1.0e-4 + (double)t * ((0.02 - 1.0e-4) / 999.0));
            acp = acp * (1.0f - beta);           // sequential fp32, like np.cumprod
            int i = (T_STEPS - 1) - t;           // loop-iteration index (reversed order)
            As[i] = sqrtf(acp);
            Bc[i] = sqrtf(1.0f - acp);
            Dc[i] = sqrtf(1.0f - ac_prev) + sqrtf(beta);
            ac_prev = acp;
        }
    }
}

// ---------------- silu time features ----------------
__global__ __launch_bounds__(256) void feats_kernel(const float* tw1, const float* tb1, float* s) {
    int idx = blockIdx.x * 256 + threadIdx.x;
    if (idx < T_STEPS * 512) {
        int t = idx >> 9, m = idx & 511;
        float a = (float)t * tw1[m] + tb1[m];
        s[idx] = a / (1.0f + expf(-a));
    }
}

// ---------------- fp32 GEMM: C[M,512] = A[M,512] @ B[512,512] + bias ----------------
__global__ __launch_bounds__(256) void gemm_kernel(const float* A, const float* B,
                                                   const float* bias, float* C, int M) {
    __shared__ float Asm[16][68];
    __shared__ float Bsm[16][68];
    int tx = threadIdx.x & 15, ty = threadIdx.x >> 4;
    int m0 = blockIdx.x * 64, n0 = blockIdx.y * 64;
    float acc[4][4] = {};
    for (int k0 = 0; k0 < 512; k0 += 16) {
        for (int l = 0; l < 4; ++l) {
            int e = threadIdx.x + l * 256;
            int mm = e >> 4, kk = e & 15;
            Asm[kk][mm] = (m0 + mm < M) ? A[(size_t)(m0 + mm) * 512 + k0 + kk] : 0.0f;
            int nn = e & 63, kk2 = e >> 6;
            Bsm[kk2][nn] = B[(size_t)(k0 + kk2) * 512 + n0 + nn];
        }
        __syncthreads();
        for (int kk = 0; kk < 16; ++kk) {
            float a[4], b[4];
            for (int i = 0; i < 4; ++i) a[i] = Asm[kk][ty * 4 + i];
            for (int j = 0; j < 4; ++j) b[j] = Bsm[kk][tx * 4 + j];
            for (int i = 0; i < 4; ++i)
                for (int j = 0; j < 4; ++j) acc[i][j] += a[i] * b[j];
        }
        __syncthreads();
    }
    for (int i = 0; i < 4; ++i) {
        int m = m0 + ty * 4 + i;
        if (m < M)
            for (int j = 0; j < 4; ++j) {
                int n = n0 + tx * 4 + j;
                C[(size_t)m * 512 + n] = acc[i][j] + bias[n];
            }
    }
}

// ---------------- transpose + 3-limb bf16 split of a 512x512 weight ----------------
__global__ __launch_bounds__(256) void tconv3_kernel(const float* w, short* ph, short* pm, short* pl) {
    int idx = blockIdx.x * 256 + threadIdx.x;  // idx = n*512 + k
    if (idx < 512 * 512) {
        int n = idx >> 9, k = idx & 511;
        float v = w[(size_t)k * 512 + n];
        unsigned short hb, mb, lb;
        split3(v, hb, mb, lb);
        ph[idx] = (short)hb; pm[idx] = (short)mb; pl[idx] = (short)lb;
    }
}

#define MFMA(a, b, c) __builtin_amdgcn_mfma_f32_16x16x32_bf16((a), (b), (c), 0, 0, 0)

// ---------------- main 1000-step loop ----------------
__global__ __launch_bounds__(512) void diffusion_main(
    const float* x0,
    const short* w1h, const short* w1m, const short* w1l,
    const short* w2h, const short* w2m, const short* w2l,
    short* xg,                       // per-block x limb planes: [blk][3][16][512]
    const float* tep, const float* nb2,
    const float* As, const float* Bc, const float* Dc,
    const float* dw1, const float* db1, const float* dw2, const float* db2,
    const float* ew1, const float* eb1, const float* ew2, const float* eb2,
    float* out) {

    // LDS: loop phase = h limb planes 3 x [16][520] shorts (49,920 B)
    // epilogue overlay: xf[16][512] f32 (32,768) + hid[16][260] f32 (16,640)
    __shared__ __align__(16) char smem[49920];
    short* hh = (short*)smem;
    short* hm = (short*)(smem + 16640);
    short* hl = (short*)(smem + 33280);
    float (*xf)[512]  = (float(*)[512])smem;
    float (*hid)[260] = (float(*)[260])(smem + 32768);

    const int tid = threadIdx.x;
    const int wave = tid >> 6;
    const int lane = tid & 63;
    const int l15 = lane & 15;
    const int lg = lane >> 4;          // 0..3
    const int strip0 = wave * 64;
    const int b0 = blockIdx.x * 16;

    short* xgb = xg + (size_t)blockIdx.x * 3 * 16 * 512;  // plane stride 8192, row stride 512

    // x fp32 master in registers (C/D layout): xr[nt][r] -> row m=lg*4+r, col n=strip0+nt*16+l15
    float xr[4][4];
    float nb2r[4];
    for (int nt = 0; nt < 4; ++nt) {
        int n = strip0 + nt * 16 + l15;
        nb2r[nt] = nb2[n];
        for (int r = 0; r < 4; ++r) {
            int m = lg * 4 + r;
            float v = x0[(size_t)(b0 + m) * 512 + n];
            xr[nt][r] = v;
            unsigned short hb, mb, lb;
            split3(v, hb, mb, lb);
            xgb[0 * 8192 + m * 512 + n] = (short)hb;
            xgb[1 * 8192 + m * 512 + n] = (short)mb;
            xgb[2 * 8192 + m * 512 + n] = (short)lb;
        }
    }
    __syncthreads();

    const int woff = (strip0 + l15) * 512 + lg * 8;  // weight tile-0 offset; tile nt adds nt*8192

#pragma unroll 1
    for (int i = 0; i < T_STEPS; ++i) {
        const int t = (T_STEPS - 1) - i;
        const float* teprow = tep + (size_t)t * 512;

        float tep_r[4];
#pragma unroll
        for (int nt = 0; nt < 4; ++nt) tep_r[nt] = teprow[strip0 + nt * 16 + l15];

        // ---- GEMM1: h = relu(x @ W1 + tep[t]), x limbs from global, W1 limbs from global ----
        f32x4 acc[4];
#pragma unroll
        for (int nt = 0; nt < 4; ++nt) acc[nt] = (f32x4){0.f, 0.f, 0.f, 0.f};
#pragma unroll
        for (int k0 = 0; k0 < 512; k0 += 32) {
            const short* xa = xgb + l15 * 512 + k0 + lg * 8;
            bf16x8 ah = *(const bf16x8*)(xa);
            bf16x8 am = *(const bf16x8*)(xa + 8192);
            bf16x8 al = *(const bf16x8*)(xa + 16384);
#pragma unroll
            for (int nt = 0; nt < 4; ++nt) {
                int wo = woff + nt * 8192 + k0;
                bf16x8 bh = *(const bf16x8*)(w1h + wo);
                bf16x8 bm = *(const bf16x8*)(w1m + wo);
                bf16x8 bl = *(const bf16x8*)(w1l + wo);
                acc[nt] = MFMA(ah, bh, acc[nt]);
                acc[nt] = MFMA(ah, bm, acc[nt]);
                acc[nt] = MFMA(am, bh, acc[nt]);
                acc[nt] = MFMA(ah, bl, acc[nt]);
                acc[nt] = MFMA(am, bm, acc[nt]);
                acc[nt] = MFMA(al, bh, acc[nt]);
            }
        }
#pragma unroll
        for (int nt = 0; nt < 4; ++nt) {
            int n = strip0 + nt * 16 + l15;
#pragma unroll
            for (int r = 0; r < 4; ++r) {
                float hv = acc[nt][r] + tep_r[nt];
                hv = hv > 0.f ? hv : 0.f;
                unsigned short hb, mb, lb;
                split3(hv, hb, mb, lb);
                int o = (lg * 4 + r) * 520 + n;
                hh[o] = (short)hb; hm[o] = (short)mb; hl[o] = (short)lb;
            }
        }
        __syncthreads();

        // ---- GEMM2: eps = h @ W2 + nb2; x update ----
#pragma unroll
        for (int nt = 0; nt < 4; ++nt) acc[nt] = (f32x4){0.f, 0.f, 0.f, 0.f};
#pragma unroll
        for (int k0 = 0; k0 < 512; k0 += 32) {
            int ho = l15 * 520 + k0 + lg * 8;
            bf16x8 ah = *(const bf16x8*)(hh + ho);
            bf16x8 am = *(const bf16x8*)(hm + ho);
            bf16x8 al = *(const bf16x8*)(hl + ho);
#pragma unroll
            for (int nt = 0; nt < 4; ++nt) {
                int wo = woff + nt * 8192 + k0;
                bf16x8 bh = *(const bf16x8*)(w2h + wo);
                bf16x8 bm = *(const bf16x8*)(w2m + wo);
                bf16x8 bl = *(const bf16x8*)(w2l + wo);
                acc[nt] = MFMA(ah, bh, acc[nt]);
                acc[nt] = MFMA(ah, bm, acc[nt]);
                acc[nt] = MFMA(am, bh, acc[nt]);
                acc[nt] = MFMA(ah, bl, acc[nt]);
                acc[nt] = MFMA(am, bm, acc[nt]);
                acc[nt] = MFMA(al, bh, acc[nt]);
            }
        }
        {
            float a_s = As[i], bc = Bc[i], dc = Dc[i];
#pragma unroll
            for (int nt = 0; nt < 4; ++nt) {
                int n = strip0 + nt * 16 + l15;
#pragma unroll
                for (int r = 0; r < 4; ++r) {
                    float eps = acc[nt][r] + nb2r[nt];
                    float be = bc * eps;
                    float de = dc * eps;
                    float xv = (xr[nt][r] - be) / a_s + de;
                    xv = fminf(fmaxf(xv, -1000.0f), 1000.0f);
                    xr[nt][r] = xv;
                    unsigned short hb, mb, lb;
                    split3(xv, hb, mb, lb);
                    int m = lg * 4 + r;
                    xgb[0 * 8192 + m * 512 + n] = (short)hb;
                    xgb[1 * 8192 + m * 512 + n] = (short)mb;
                    xgb[2 * 8192 + m * 512 + n] = (short)lb;
                }
            }
        }
        __syncthreads();
    }

    // ---- epilogue: dump fp32 x, head GEMMs, write output (pitch 515) ----
    for (int nt = 0; nt < 4; ++nt) {
        int n = strip0 + nt * 16 + l15;
        for (int r = 0; r < 4; ++r) xf[lg * 4 + r][n] = xr[nt][r];
    }
    __syncthreads();

    {   // depth head: hid = relu(x @ dw1 + db1)
        int c = tid & 255;
        int r0 = (tid >> 8) * 8;
        float a8[8];
        for (int j = 0; j < 8; ++j) a8[j] = 0.f;
        for (int k = 0; k < 512; ++k) {
            float w = dw1[(size_t)k * 256 + c];
            for (int j = 0; j < 8; ++j) a8[j] += xf[r0 + j][k] * w;
        }
        float bv = db1[c];
        for (int j = 0; j < 8; ++j) {
            float hv = a8[j] + bv;
            hid[r0 + j][c] = hv > 0.f ? hv : 0.f;
        }
    }
    __syncthreads();
    if (tid < 16) {
        float s = db2[0];
        for (int c = 0; c < 256; ++c) s += hid[tid][c] * dw2[c];
        out[(size_t)(b0 + tid) * 515] = s;
    }
    __syncthreads();
    {   // emotion head
        int c = tid & 255;
        int r0 = (tid >> 8) * 8;
        float a8[8];
        for (int j = 0; j < 8; ++j) a8[j] = 0.f;
        for (int k = 0; k < 512; ++k) {
            float w = ew1[(size_t)k * 256 + c];
            for (int j = 0; j < 8; ++j) a8[j] += xf[r0 + j][k] * w;
        }
        float bv = eb1[c];
        for (int j = 0; j < 8; ++j) {
            float hv = a8[j] + bv;
            hid[r0 + j][c] = hv > 0.f ? hv : 0.f;
        }
    }
    __syncthreads();
    if (tid < 16) {
        float s1 = eb2[0], s2 = eb2[1];
        for (int c = 0; c < 256; ++c) {
            float hv = hid[tid][c];
            s1 += hv * ew2[2 * c];
            s2 += hv * ew2[2 * c + 1];
        }
        out[(size_t)(b0 + tid) * 515 + 1] = s1;
        out[(size_t)(b0 + tid) * 515 + 2] = s2;
    }
    for (int e = tid; e < 16 * 512; e += 512) {
        int r = e >> 9, k = e & 511;
        out[(size_t)(b0 + r) * 515 + 3 + k] = xf[r][k];
    }
}

extern "C" void kernel_launch(void* const* d_in, const int* in_sizes, int n_in,
                              void* d_out, int out_size, void* d_ws, size_t ws_size,
                              hipStream_t stream) {
    const float* x0  = (const float*)d_in[0];
    const float* tw1 = (const float*)d_in[1];
    const float* tb1 = (const float*)d_in[2];
    const float* tw2 = (const float*)d_in[3];
    const float* tb2 = (const float*)d_in[4];
    const float* nw1 = (const float*)d_in[5];
    const float* nb1 = (const float*)d_in[6];
    const float* nw2 = (const float*)d_in[7];
    const float* nb2 = (const float*)d_in[8];
    const float* dw1 = (const float*)d_in[9];
    const float* db1 = (const float*)d_in[10];
    const float* dw2 = (const float*)d_in[11];
    const float* db2 = (const float*)d_in[12];
    const float* ew1 = (const float*)d_in[13];
    const float* eb1 = (const float*)d_in[14];
    const float* ew2 = (const float*)d_in[15];
    const float* eb2 = (const float*)d_in[16];
    float* out = (float*)d_out;

    float* ws    = (float*)d_ws;
    float* sfeat = ws;                   // 512000 f
    float* te    = sfeat + 512000;       // 512000 f
    float* tep   = te + 512000;          // 512000 f
    float* Asv   = tep + 512000;         // 1024 f each
    float* Bcv   = Asv + 1024;
    float* Dcv   = Bcv + 1024;
    short* w1h   = (short*)(Dcv + 1024); // 6 planes x 262144 shorts
    short* w1m   = w1h + 262144;
    short* w1l   = w1m + 262144;
    short* w2h   = w1l + 262144;
    short* w2m   = w2h + 262144;
    short* w2l   = w2m + 262144;
    short* xg    = w2l + 262144;         // 16 blocks x 3 x 16 x 512 shorts

    hipLaunchKernelGGL(scalars_kernel, dim3(1), dim3(64), 0, stream, Asv, Bcv, Dcv);
    hipLaunchKernelGGL(feats_kernel, dim3(2000), dim3(256), 0, stream, tw1, tb1, sfeat);
    hipLaunchKernelGGL(gemm_kernel, dim3(16, 8), dim3(256), 0, stream, sfeat, tw2, tb2, te, 1000);
    hipLaunchKernelGGL(gemm_kernel, dim3(16, 8), dim3(256), 0, stream, te, nw1 + 512 * 512, nb1, tep, 1000);
    hipLaunchKernelGGL(tconv3_kernel, dim3(1024), dim3(256), 0, stream, nw1, w1h, w1m, w1l);
    hipLaunchKernelGGL(tconv3_kernel, dim3(1024), dim3(256), 0, stream, nw2, w2h, w2m, w2l);
    hipLaunchKernelGGL(diffusion_main, dim3(16), dim3(512), 0, stream,
                       x0, w1h, w1m, w1l, w2h, w2m, w2l, xg, tep, nb2,
                       Asv, Bcv, Dcv,
                       dw1, db1, dw2, db2, ew1, eb1, ew2, eb2, out);
}

// Round 3
// 57113.141 us; speedup vs baseline: 2.6000x; 2.6000x over previous
//
#include <hip/hip_runtime.h>
#include <stdint.h>
#include <math.h>

#define T_STEPS 1000

typedef __attribute__((ext_vector_type(4))) float f32x4;
typedef __attribute__((ext_vector_type(8))) _Float16 f16x8;

#define C_2M11 4.8828125e-4f        // 2^-11
#define C_2M22 2.384185791015625e-7f // 2^-22
#define F16_MINNORM 6.103515625e-05f

// split fp32 -> hi fp16 + lo fp16 (lo pre-scaled by 2^11, stays normal-range)
__device__ __forceinline__ void split2h(float v, _Float16& hi, _Float16& lo) {
    float av = fabsf(v);
    _Float16 h = (av < F16_MINNORM) ? (_Float16)0.0f : (_Float16)v;
    float r = v - (float)h;
    hi = h;
    lo = (_Float16)(r * 2048.0f);
}

// ---------------- coefficients: fp32 cumprod (matches np.cumprod) ----------------
__global__ void scalars_kernel(float* As, float* Bc, float* Dc) {
    if (threadIdx.x == 0 && blockIdx.x == 0) {
        float acp = 1.0f;
        float ac_prev = 1.0f;
        for (int t = 0; t < T_STEPS; ++t) {
            float beta = (float)(1.0e-4 + (double)t * ((0.02 - 1.0e-4) / 999.0));
            acp = acp * (1.0f - beta);
            int i = (T_STEPS - 1) - t;
            As[i] = sqrtf(acp);
            Bc[i] = sqrtf(1.0f - acp);
            Dc[i] = sqrtf(1.0f - ac_prev) + sqrtf(beta);
            ac_prev = acp;
        }
    }
}

// ---------------- silu time features ----------------
__global__ __launch_bounds__(256) void feats_kernel(const float* tw1, const float* tb1, float* s) {
    int idx = blockIdx.x * 256 + threadIdx.x;
    if (idx < T_STEPS * 512) {
        int t = idx >> 9, m = idx & 511;
        float a = (float)t * tw1[m] + tb1[m];
        s[idx] = a / (1.0f + expf(-a));
    }
}

// ---------------- fp32 GEMM: C[M,512] = A[M,512] @ B[512,512] + bias ----------------
__global__ __launch_bounds__(256) void gemm_kernel(const float* A, const float* B,
                                                   const float* bias, float* C, int M) {
    __shared__ float Asm[16][68];
    __shared__ float Bsm[16][68];
    int tx = threadIdx.x & 15, ty = threadIdx.x >> 4;
    int m0 = blockIdx.x * 64, n0 = blockIdx.y * 64;
    float acc[4][4] = {};
    for (int k0 = 0; k0 < 512; k0 += 16) {
        for (int l = 0; l < 4; ++l) {
            int e = threadIdx.x + l * 256;
            int mm = e >> 4, kk = e & 15;
            Asm[kk][mm] = (m0 + mm < M) ? A[(size_t)(m0 + mm) * 512 + k0 + kk] : 0.0f;
            int nn = e & 63, kk2 = e >> 6;
            Bsm[kk2][nn] = B[(size_t)(k0 + kk2) * 512 + n0 + nn];
        }
        __syncthreads();
        for (int kk = 0; kk < 16; ++kk) {
            float a[4], b[4];
            for (int i = 0; i < 4; ++i) a[i] = Asm[kk][ty * 4 + i];
            for (int j = 0; j < 4; ++j) b[j] = Bsm[kk][tx * 4 + j];
            for (int i = 0; i < 4; ++i)
                for (int j = 0; j < 4; ++j) acc[i][j] += a[i] * b[j];
        }
        __syncthreads();
    }
    for (int i = 0; i < 4; ++i) {
        int m = m0 + ty * 4 + i;
        if (m < M)
            for (int j = 0; j < 4; ++j) {
                int n = n0 + tx * 4 + j;
                C[(size_t)m * 512 + n] = acc[i][j] + bias[n];
            }
    }
}

// ---------------- transpose + 2-limb fp16 split of a 512x512 weight ----------------
__global__ __launch_bounds__(256) void tconv2_kernel(const float* w, short* ph, short* pl) {
    int idx = blockIdx.x * 256 + threadIdx.x;  // idx = n*512 + k
    if (idx < 512 * 512) {
        int n = idx >> 9, k = idx & 511;
        float v = w[(size_t)k * 512 + n];
        _Float16 hi, lo;
        split2h(v, hi, lo);
        union { _Float16 h; short s; } uh, ul;
        uh.h = hi; ul.h = lo;
        ph[idx] = uh.s;
        pl[idx] = ul.s;
    }
}

#define MFMAH(a, b, c) __builtin_amdgcn_mfma_f32_16x16x32_f16((a), (b), (c), 0, 0, 0)

// ---------------- main 1000-step loop: 16 blocks x 1024 threads ----------------
__global__ __launch_bounds__(1024) void diffusion_main(
    const float* x0,
    const short* w1h_, const short* w1l_,
    const short* w2h_, const short* w2l_,
    const float* tep, const float* nb2,
    const float* As, const float* Bc, const float* Dc,
    const float* dw1, const float* db1, const float* dw2, const float* db2,
    const float* ew1, const float* eb1, const float* ew2, const float* eb2,
    float* out) {

    // LDS loop phase: 4 planes x [16][512] fp16, XOR-swizzled in 8-element blocks.
    // plane order: xh(0) xl(8192) hh(16384) hl(24576)   (offsets in shorts)
    // Epilogue overlay: xf[16][512] f32 (32KB) + hid[16][260] f32 (16.6KB)
    __shared__ __align__(16) char smem[65536];
    _Float16* xh = (_Float16*)smem;
    _Float16* xl = xh + 8192;
    _Float16* hh = xh + 16384;
    _Float16* hl = xh + 24576;
    float (*xf)[512]  = (float(*)[512])smem;
    float (*hid)[260] = (float(*)[260])(smem + 32768);

    const int tid  = threadIdx.x;
    const int wave = tid >> 6;          // 0..15
    const int lane = tid & 63;
    const int l15  = lane & 15;
    const int lg   = lane >> 4;         // 0..3
    const int strip0 = wave * 32;       // 32-col strip, 2 tiles of 16
    const int b0 = blockIdx.x * 16;

    const _Float16* w1h = (const _Float16*)w1h_;
    const _Float16* w1l = (const _Float16*)w1l_;
    const _Float16* w2h = (const _Float16*)w2h_;
    const _Float16* w2l = (const _Float16*)w2l_;

    // per-lane weight element offsets for the 2 n-tiles (layout W^T[n][k])
    const int woff0 = (strip0 + 0 * 16 + l15) * 512 + lg * 8;
    const int woff1 = (strip0 + 1 * 16 + l15) * 512 + lg * 8;

    // x fp32 master (C/D layout): xr[nt][r] -> row m=lg*4+r, col n=strip0+nt*16+l15
    float xr[2][4];
    float nb2r[2];
    for (int nt = 0; nt < 2; ++nt) {
        int n = strip0 + nt * 16 + l15;
        nb2r[nt] = nb2[n];
        for (int r = 0; r < 4; ++r) {
            int m = lg * 4 + r;
            float v = x0[(size_t)(b0 + m) * 512 + n];
            xr[nt][r] = v;
            _Float16 hi, lo;
            split2h(v, hi, lo);
            int off = m * 512 + ((((n >> 3) ^ m) << 3) | (n & 7));
            xh[off] = hi;
            xl[off] = lo;
        }
    }
    __syncthreads();

    const int abase = l15 * 512;  // A-operand LDS row base (row = batch idx = l15)

#pragma unroll 1
    for (int i = 0; i < T_STEPS; ++i) {
        const int t = (T_STEPS - 1) - i;
        const float* teprow = tep + (size_t)t * 512;
        float tep_r[2];
        tep_r[0] = teprow[strip0 + l15];
        tep_r[1] = teprow[strip0 + 16 + l15];

        // ---- GEMM1: h = relu(x @ W1 + tep[t]) ----
        f32x4 a0[2], a1[2], a2[2];
#pragma unroll
        for (int nt = 0; nt < 2; ++nt) {
            a0[nt] = (f32x4){0.f, 0.f, 0.f, 0.f};
            a1[nt] = (f32x4){0.f, 0.f, 0.f, 0.f};
            a2[nt] = (f32x4){0.f, 0.f, 0.f, 0.f};
        }
#pragma unroll
        for (int k0 = 0; k0 < 512; k0 += 32) {
            int blk = (((k0 >> 3) + lg) ^ l15) << 3;
            f16x8 ah = *(const f16x8*)(xh + abase + blk);
            f16x8 al = *(const f16x8*)(xl + abase + blk);
            f16x8 b0h = *(const f16x8*)(w1h + woff0 + k0);
            f16x8 b0l = *(const f16x8*)(w1l + woff0 + k0);
            f16x8 b1h = *(const f16x8*)(w1h + woff1 + k0);
            f16x8 b1l = *(const f16x8*)(w1l + woff1 + k0);
            a0[0] = MFMAH(ah, b0h, a0[0]);
            a1[0] = MFMAH(ah, b0l, a1[0]);
            a1[0] = MFMAH(al, b0h, a1[0]);
            a2[0] = MFMAH(al, b0l, a2[0]);
            a0[1] = MFMAH(ah, b1h, a0[1]);
            a1[1] = MFMAH(ah, b1l, a1[1]);
            a1[1] = MFMAH(al, b1h, a1[1]);
            a2[1] = MFMAH(al, b1l, a2[1]);
        }
#pragma unroll
        for (int nt = 0; nt < 2; ++nt) {
            int n = strip0 + nt * 16 + l15;
#pragma unroll
            for (int r = 0; r < 4; ++r) {
                float hv = a0[nt][r] + a1[nt][r] * C_2M11 + a2[nt][r] * C_2M22 + tep_r[nt];
                hv = hv > 0.f ? hv : 0.f;
                _Float16 hi, lo;
                split2h(hv, hi, lo);
                int m = lg * 4 + r;
                int off = m * 512 + ((((n >> 3) ^ m) << 3) | (n & 7));
                hh[off] = hi;
                hl[off] = lo;
            }
        }
        __syncthreads();

        // ---- GEMM2: eps = h @ W2 + nb2; x update ----
#pragma unroll
        for (int nt = 0; nt < 2; ++nt) {
            a0[nt] = (f32x4){0.f, 0.f, 0.f, 0.f};
            a1[nt] = (f32x4){0.f, 0.f, 0.f, 0.f};
            a2[nt] = (f32x4){0.f, 0.f, 0.f, 0.f};
        }
#pragma unroll
        for (int k0 = 0; k0 < 512; k0 += 32) {
            int blk = (((k0 >> 3) + lg) ^ l15) << 3;
            f16x8 ah = *(const f16x8*)(hh + abase + blk);
            f16x8 al = *(const f16x8*)(hl + abase + blk);
            f16x8 b0h = *(const f16x8*)(w2h + woff0 + k0);
            f16x8 b0l = *(const f16x8*)(w2l + woff0 + k0);
            f16x8 b1h = *(const f16x8*)(w2h + woff1 + k0);
            f16x8 b1l = *(const f16x8*)(w2l + woff1 + k0);
            a0[0] = MFMAH(ah, b0h, a0[0]);
            a1[0] = MFMAH(ah, b0l, a1[0]);
            a1[0] = MFMAH(al, b0h, a1[0]);
            a2[0] = MFMAH(al, b0l, a2[0]);
            a0[1] = MFMAH(ah, b1h, a0[1]);
            a1[1] = MFMAH(ah, b1l, a1[1]);
            a1[1] = MFMAH(al, b1h, a1[1]);
            a2[1] = MFMAH(al, b1l, a2[1]);
        }
        {
            float a_s = As[i], bc = Bc[i], dc = Dc[i];
#pragma unroll
            for (int nt = 0; nt < 2; ++nt) {
                int n = strip0 + nt * 16 + l15;
#pragma unroll
                for (int r = 0; r < 4; ++r) {
                    float eps = a0[nt][r] + a1[nt][r] * C_2M11 + a2[nt][r] * C_2M22 + nb2r[nt];
                    float xv = (xr[nt][r] - bc * eps) / a_s + dc * eps;
                    xv = fminf(fmaxf(xv, -1000.0f), 1000.0f);
                    xr[nt][r] = xv;
                    _Float16 hi, lo;
                    split2h(xv, hi, lo);
                    int m = lg * 4 + r;
                    int off = m * 512 + ((((n >> 3) ^ m) << 3) | (n & 7));
                    xh[off] = hi;
                    xl[off] = lo;
                }
            }
        }
        __syncthreads();
    }

    // ---- epilogue: dump fp32 x, head GEMMs, write output (pitch 515) ----
    __syncthreads();
    {
        // stash xr to registers is already done; write xf (overlays limb planes)
        float tmp[2][4];
        for (int nt = 0; nt < 2; ++nt)
            for (int r = 0; r < 4; ++r) tmp[nt][r] = xr[nt][r];
        __syncthreads();
        for (int nt = 0; nt < 2; ++nt) {
            int n = strip0 + nt * 16 + l15;
            for (int r = 0; r < 4; ++r) xf[lg * 4 + r][n] = tmp[nt][r];
        }
    }
    __syncthreads();

    {   // depth head: hid = relu(x @ dw1 + db1), dw1 is 512x256; 4 groups x 4 rows
        int c = tid & 255;
        int r0 = (tid >> 8) * 4;
        float a4[4] = {0.f, 0.f, 0.f, 0.f};
        for (int k = 0; k < 512; ++k) {
            float w = dw1[(size_t)k * 256 + c];
            for (int j = 0; j < 4; ++j) a4[j] += xf[r0 + j][k] * w;
        }
        float bv = db1[c];
        for (int j = 0; j < 4; ++j) {
            float hv = a4[j] + bv;
            hid[r0 + j][c] = hv > 0.f ? hv : 0.f;
        }
    }
    __syncthreads();
    if (tid < 16) {
        float s = db2[0];
        for (int c = 0; c < 256; ++c) s += hid[tid][c] * dw2[c];
        out[(size_t)(b0 + tid) * 515] = s;
    }
    __syncthreads();
    {   // emotion head
        int c = tid & 255;
        int r0 = (tid >> 8) * 4;
        float a4[4] = {0.f, 0.f, 0.f, 0.f};
        for (int k = 0; k < 512; ++k) {
            float w = ew1[(size_t)k * 256 + c];
            for (int j = 0; j < 4; ++j) a4[j] += xf[r0 + j][k] * w;
        }
        float bv = eb1[c];
        for (int j = 0; j < 4; ++j) {
            float hv = a4[j] + bv;
            hid[r0 + j][c] = hv > 0.f ? hv : 0.f;
        }
    }
    __syncthreads();
    if (tid < 16) {
        float s1 = eb2[0], s2 = eb2[1];
        for (int c = 0; c < 256; ++c) {
            float hv = hid[tid][c];
            s1 += hv * ew2[2 * c];
            s2 += hv * ew2[2 * c + 1];
        }
        out[(size_t)(b0 + tid) * 515 + 1] = s1;
        out[(size_t)(b0 + tid) * 515 + 2] = s2;
    }
    for (int e = tid; e < 16 * 512; e += 1024) {
        int r = e >> 9, k = e & 511;
        out[(size_t)(b0 + r) * 515 + 3 + k] = xf[r][k];
    }
}

extern "C" void kernel_launch(void* const* d_in, const int* in_sizes, int n_in,
                              void* d_out, int out_size, void* d_ws, size_t ws_size,
                              hipStream_t stream) {
    const float* x0  = (const float*)d_in[0];
    const float* tw1 = (const float*)d_in[1];
    const float* tb1 = (const float*)d_in[2];
    const float* tw2 = (const float*)d_in[3];
    const float* tb2 = (const float*)d_in[4];
    const float* nw1 = (const float*)d_in[5];
    const float* nb1 = (const float*)d_in[6];
    const float* nw2 = (const float*)d_in[7];
    const float* nb2 = (const float*)d_in[8];
    const float* dw1 = (const float*)d_in[9];
    const float* db1 = (const float*)d_in[10];
    const float* dw2 = (const float*)d_in[11];
    const float* db2 = (const float*)d_in[12];
    const float* ew1 = (const float*)d_in[13];
    const float* eb1 = (const float*)d_in[14];
    const float* ew2 = (const float*)d_in[15];
    const float* eb2 = (const float*)d_in[16];
    float* out = (float*)d_out;

    float* ws    = (float*)d_ws;
    float* sfeat = ws;                   // 512000 f
    float* te    = sfeat + 512000;       // 512000 f
    float* tep   = te + 512000;          // 512000 f
    float* Asv   = tep + 512000;         // 1024 f each
    float* Bcv   = Asv + 1024;
    float* Dcv   = Bcv + 1024;
    short* w1h   = (short*)(Dcv + 1024); // 4 planes x 262144 shorts
    short* w1l   = w1h + 262144;
    short* w2h   = w1l + 262144;
    short* w2l   = w2h + 262144;

    hipLaunchKernelGGL(scalars_kernel, dim3(1), dim3(64), 0, stream, Asv, Bcv, Dcv);
    hipLaunchKernelGGL(feats_kernel, dim3(2000), dim3(256), 0, stream, tw1, tb1, sfeat);
    hipLaunchKernelGGL(gemm_kernel, dim3(16, 8), dim3(256), 0, stream, sfeat, tw2, tb2, te, 1000);
    hipLaunchKernelGGL(gemm_kernel, dim3(16, 8), dim3(256), 0, stream, te, nw1 + 512 * 512, nb1, tep, 1000);
    hipLaunchKernelGGL(tconv2_kernel, dim3(1024), dim3(256), 0, stream, nw1, w1h, w1l);
    hipLaunchKernelGGL(tconv2_kernel, dim3(1024), dim3(256), 0, stream, nw2, w2h, w2l);
    hipLaunchKernelGGL(diffusion_main, dim3(16), dim3(1024), 0, stream,
                       x0, w1h, w1l, w2h, w2l, tep, nb2,
                       Asv, Bcv, Dcv,
                       dw1, db1, dw2, db2, ew1, eb1, ew2, eb2, out);
}

// Round 4
// 49583.212 us; speedup vs baseline: 2.9949x; 1.1519x over previous
//
#include <hip/hip_runtime.h>
#include <stdint.h>
#include <math.h>

#define T_STEPS 1000

typedef __attribute__((ext_vector_type(4))) float f32x4;
typedef __attribute__((ext_vector_type(8))) _Float16 f16x8;

#define C_2M11 4.8828125e-4f         // 2^-11
#define C_2M22 2.384185791015625e-7f // 2^-22
#define F16_MINNORM 6.103515625e-05f

// soft workgroup barrier: drain LDS ops only, leave global loads in flight
#define SOFT_BARRIER() asm volatile("s_waitcnt lgkmcnt(0)\n\ts_barrier" ::: "memory")

// split fp32 -> hi fp16 + lo fp16 (lo pre-scaled by 2^11, stays normal-range)
__device__ __forceinline__ void split2h(float v, _Float16& hi, _Float16& lo) {
    float av = fabsf(v);
    _Float16 h = (av < F16_MINNORM) ? (_Float16)0.0f : (_Float16)v;
    float r = v - (float)h;
    hi = h;
    lo = (_Float16)(r * 2048.0f);
}

// ---------------- coefficients: fp32 cumprod (matches np.cumprod) ----------------
__global__ void scalars_kernel(float* As, float* Bc, float* Dc) {
    if (threadIdx.x == 0 && blockIdx.x == 0) {
        float acp = 1.0f;
        float ac_prev = 1.0f;
        for (int t = 0; t < T_STEPS; ++t) {
            float beta = (float)(1.0e-4 + (double)t * ((0.02 - 1.0e-4) / 999.0));
            acp = acp * (1.0f - beta);
            int i = (T_STEPS - 1) - t;
            As[i] = sqrtf(acp);
            Bc[i] = sqrtf(1.0f - acp);
            Dc[i] = sqrtf(1.0f - ac_prev) + sqrtf(beta);
            ac_prev = acp;
        }
    }
}

// ---------------- silu time features ----------------
__global__ __launch_bounds__(256) void feats_kernel(const float* tw1, const float* tb1, float* s) {
    int idx = blockIdx.x * 256 + threadIdx.x;
    if (idx < T_STEPS * 512) {
        int t = idx >> 9, m = idx & 511;
        float a = (float)t * tw1[m] + tb1[m];
        s[idx] = a / (1.0f + expf(-a));
    }
}

// ---------------- fp32 GEMM: C[M,512] = A[M,512] @ B[512,512] + bias ----------------
__global__ __launch_bounds__(256) void gemm_kernel(const float* A, const float* B,
                                                   const float* bias, float* C, int M) {
    __shared__ float Asm[16][68];
    __shared__ float Bsm[16][68];
    int tx = threadIdx.x & 15, ty = threadIdx.x >> 4;
    int m0 = blockIdx.x * 64, n0 = blockIdx.y * 64;
    float acc[4][4] = {};
    for (int k0 = 0; k0 < 512; k0 += 16) {
        for (int l = 0; l < 4; ++l) {
            int e = threadIdx.x + l * 256;
            int mm = e >> 4, kk = e & 15;
            Asm[kk][mm] = (m0 + mm < M) ? A[(size_t)(m0 + mm) * 512 + k0 + kk] : 0.0f;
            int nn = e & 63, kk2 = e >> 6;
            Bsm[kk2][nn] = B[(size_t)(k0 + kk2) * 512 + n0 + nn];
        }
        __syncthreads();
        for (int kk = 0; kk < 16; ++kk) {
            float a[4], b[4];
            for (int i = 0; i < 4; ++i) a[i] = Asm[kk][ty * 4 + i];
            for (int j = 0; j < 4; ++j) b[j] = Bsm[kk][tx * 4 + j];
            for (int i = 0; i < 4; ++i)
                for (int j = 0; j < 4; ++j) acc[i][j] += a[i] * b[j];
        }
        __syncthreads();
    }
    for (int i = 0; i < 4; ++i) {
        int m = m0 + ty * 4 + i;
        if (m < M)
            for (int j = 0; j < 4; ++j) {
                int n = n0 + tx * 4 + j;
                C[(size_t)m * 512 + n] = acc[i][j] + bias[n];
            }
    }
}

// ---------------- pack weight into fragment-order chunks + 2-limb fp16 split ----------------
// packed element index p: chunk = p>>9 (= ntile*16 + kb), inchunk = p&511 = (n&15)*32 + (k&31)
__global__ __launch_bounds__(256) void tpack_kernel(const float* w, short* ph, short* pl) {
    int p = blockIdx.x * 256 + threadIdx.x;
    if (p < 512 * 512) {
        int chunk = p >> 9, inch = p & 511;
        int n = (chunk >> 4) * 16 + (inch >> 5);
        int k = (chunk & 15) * 32 + (inch & 31);
        float v = w[(size_t)k * 512 + n];
        _Float16 hi, lo;
        split2h(v, hi, lo);
        union { _Float16 h; short s; } uh, ul;
        uh.h = hi; ul.h = lo;
        ph[p] = uh.s;
        pl[p] = ul.s;
    }
}

#define MFMAH(a, b, c) __builtin_amdgcn_mfma_f32_16x16x32_f16((a), (b), (c), 0, 0, 0)

// ---------------- main 1000-step loop: 16 blocks x 1024 threads ----------------
__global__ __launch_bounds__(1024) void diffusion_main(
    const float* x0,
    const short* w1h_, const short* w1l_,
    const short* w2h_, const short* w2l_,
    const float* tep, const float* nb2,
    const float* As, const float* Bc, const float* Dc,
    const float* dw1, const float* db1, const float* dw2, const float* db2,
    const float* ew1, const float* eb1, const float* ew2, const float* eb2,
    float* out) {

    // LDS loop phase: 4 planes x [16][512] fp16, XOR-swizzled in 8-element blocks.
    // Epilogue overlay: xf[16][512] f32 + hid[16][260] f32
    __shared__ __align__(16) char smem[65536];
    _Float16* xh = (_Float16*)smem;
    _Float16* xl = xh + 8192;
    _Float16* hh = xh + 16384;
    _Float16* hl = xh + 24576;
    float (*xf)[512]  = (float(*)[512])smem;
    float (*hid)[260] = (float(*)[260])(smem + 32768);

    const int tid  = threadIdx.x;
    const int wave = tid >> 6;          // 0..15
    const int lane = tid & 63;
    const int l15  = lane & 15;
    const int lg   = lane >> 4;         // 0..3
    const int strip0 = wave * 32;       // 32-col strip = 2 n-tiles
    const int b0 = blockIdx.x * 16;

    const _Float16* w1h = (const _Float16*)w1h_;
    const _Float16* w1l = (const _Float16*)w1l_;
    const _Float16* w2h = (const _Float16*)w2h_;
    const _Float16* w2l = (const _Float16*)w2l_;

    // packed-chunk element offsets: nt tile base = (wave*2+nt)*16 chunks of 512 elems
    const int lane_off = l15 * 32 + lg * 8;
    const int ob0 = wave * 16384 + lane_off;          // nt=0, kb=0
    const int ob1 = ob0 + 8192;                       // nt=1, kb=0

    // x fp32 master (C/D layout): xr[nt][r] -> row m=lg*4+r, col n=strip0+nt*16+l15
    float xr[2][4];
    float nb2r[2];
    for (int nt = 0; nt < 2; ++nt) {
        int n = strip0 + nt * 16 + l15;
        nb2r[nt] = nb2[n];
        for (int r = 0; r < 4; ++r) {
            int m = lg * 4 + r;
            float v = x0[(size_t)(b0 + m) * 512 + n];
            xr[nt][r] = v;
            _Float16 hi, lo;
            split2h(v, hi, lo);
            int off = m * 512 + ((((n >> 3) ^ m) << 3) | (n & 7));
            xh[off] = hi;
            xl[off] = lo;
        }
    }
    __syncthreads();

    const int abase = l15 * 512;  // A-operand LDS row base (row = batch idx = l15)

    // weight double-buffer: [0]=h nt0, [1]=l nt0, [2]=h nt1, [3]=l nt1
    f16x8 wbuf[2][4];
    wbuf[0][0] = *(const f16x8*)(w1h + ob0);
    wbuf[0][1] = *(const f16x8*)(w1l + ob0);
    wbuf[0][2] = *(const f16x8*)(w1h + ob1);
    wbuf[0][3] = *(const f16x8*)(w1l + ob1);

#pragma unroll 1
    for (int i = 0; i < T_STEPS; ++i) {
        const int t = (T_STEPS - 1) - i;
        const float* teprow = tep + (size_t)t * 512;
        float tep_r[2];
        tep_r[0] = teprow[strip0 + l15];
        tep_r[1] = teprow[strip0 + 16 + l15];
        float a_s = As[i], bc = Bc[i], dc = Dc[i];

        f32x4 a0[2], a1[2], a2[2];
#pragma unroll
        for (int nt = 0; nt < 2; ++nt) {
            a0[nt] = (f32x4){0.f, 0.f, 0.f, 0.f};
            a1[nt] = (f32x4){0.f, 0.f, 0.f, 0.f};
            a2[nt] = (f32x4){0.f, 0.f, 0.f, 0.f};
        }

        // ---- GEMM1: h = relu(x @ W1 + tep[t]) ----
#pragma unroll
        for (int kb = 0; kb < 16; ++kb) {
            const int cur = kb & 1, nxt = cur ^ 1;
            if (kb < 15) {
                int o = (kb + 1) * 512;
                wbuf[nxt][0] = *(const f16x8*)(w1h + ob0 + o);
                wbuf[nxt][1] = *(const f16x8*)(w1l + ob0 + o);
                wbuf[nxt][2] = *(const f16x8*)(w1h + ob1 + o);
                wbuf[nxt][3] = *(const f16x8*)(w1l + ob1 + o);
            } else {  // prefetch GEMM2 kb=0
                wbuf[nxt][0] = *(const f16x8*)(w2h + ob0);
                wbuf[nxt][1] = *(const f16x8*)(w2l + ob0);
                wbuf[nxt][2] = *(const f16x8*)(w2h + ob1);
                wbuf[nxt][3] = *(const f16x8*)(w2l + ob1);
            }
            int blk = ((kb * 4 + lg) ^ l15) << 3;
            f16x8 ah = *(const f16x8*)(xh + abase + blk);
            f16x8 al = *(const f16x8*)(xl + abase + blk);
            a0[0] = MFMAH(ah, wbuf[cur][0], a0[0]);
            a1[0] = MFMAH(ah, wbuf[cur][1], a1[0]);
            a1[0] = MFMAH(al, wbuf[cur][0], a1[0]);
            a2[0] = MFMAH(al, wbuf[cur][1], a2[0]);
            a0[1] = MFMAH(ah, wbuf[cur][2], a0[1]);
            a1[1] = MFMAH(ah, wbuf[cur][3], a1[1]);
            a1[1] = MFMAH(al, wbuf[cur][2], a1[1]);
            a2[1] = MFMAH(al, wbuf[cur][3], a2[1]);
        }
#pragma unroll
        for (int nt = 0; nt < 2; ++nt) {
            int n = strip0 + nt * 16 + l15;
#pragma unroll
            for (int r = 0; r < 4; ++r) {
                float hv = a0[nt][r] + a1[nt][r] * C_2M11 + a2[nt][r] * C_2M22 + tep_r[nt];
                hv = hv > 0.f ? hv : 0.f;
                _Float16 hi, lo;
                split2h(hv, hi, lo);
                int m = lg * 4 + r;
                int off = m * 512 + ((((n >> 3) ^ m) << 3) | (n & 7));
                hh[off] = hi;
                hl[off] = lo;
            }
        }
        SOFT_BARRIER();

        // ---- GEMM2: eps = h @ W2 + nb2; x update ----
#pragma unroll
        for (int nt = 0; nt < 2; ++nt) {
            a0[nt] = (f32x4){0.f, 0.f, 0.f, 0.f};
            a1[nt] = (f32x4){0.f, 0.f, 0.f, 0.f};
            a2[nt] = (f32x4){0.f, 0.f, 0.f, 0.f};
        }
#pragma unroll
        for (int kb = 0; kb < 16; ++kb) {
            const int cur = kb & 1, nxt = cur ^ 1;
            if (kb < 15) {
                int o = (kb + 1) * 512;
                wbuf[nxt][0] = *(const f16x8*)(w2h + ob0 + o);
                wbuf[nxt][1] = *(const f16x8*)(w2l + ob0 + o);
                wbuf[nxt][2] = *(const f16x8*)(w2h + ob1 + o);
                wbuf[nxt][3] = *(const f16x8*)(w2l + ob1 + o);
            } else {  // prefetch next step's GEMM1 kb=0
                wbuf[nxt][0] = *(const f16x8*)(w1h + ob0);
                wbuf[nxt][1] = *(const f16x8*)(w1l + ob0);
                wbuf[nxt][2] = *(const f16x8*)(w1h + ob1);
                wbuf[nxt][3] = *(const f16x8*)(w1l + ob1);
            }
            int blk = ((kb * 4 + lg) ^ l15) << 3;
            f16x8 ah = *(const f16x8*)(hh + abase + blk);
            f16x8 al = *(const f16x8*)(hl + abase + blk);
            a0[0] = MFMAH(ah, wbuf[cur][0], a0[0]);
            a1[0] = MFMAH(ah, wbuf[cur][1], a1[0]);
            a1[0] = MFMAH(al, wbuf[cur][0], a1[0]);
            a2[0] = MFMAH(al, wbuf[cur][1], a2[0]);
            a0[1] = MFMAH(ah, wbuf[cur][2], a0[1]);
            a1[1] = MFMAH(ah, wbuf[cur][3], a1[1]);
            a1[1] = MFMAH(al, wbuf[cur][2], a1[1]);
            a2[1] = MFMAH(al, wbuf[cur][3], a2[1]);
        }
#pragma unroll
        for (int nt = 0; nt < 2; ++nt) {
            int n = strip0 + nt * 16 + l15;
#pragma unroll
            for (int r = 0; r < 4; ++r) {
                float eps = a0[nt][r] + a1[nt][r] * C_2M11 + a2[nt][r] * C_2M22 + nb2r[nt];
                float xv = (xr[nt][r] - bc * eps) / a_s + dc * eps;
                xv = fminf(fmaxf(xv, -1000.0f), 1000.0f);
                xr[nt][r] = xv;
                _Float16 hi, lo;
                split2h(xv, hi, lo);
                int m = lg * 4 + r;
                int off = m * 512 + ((((n >> 3) ^ m) << 3) | (n & 7));
                xh[off] = hi;
                xl[off] = lo;
            }
        }
        SOFT_BARRIER();
    }

    // ---- epilogue: dump fp32 x, head GEMMs, write output (pitch 515) ----
    __syncthreads();
    {
        float tmp[2][4];
        for (int nt = 0; nt < 2; ++nt)
            for (int r = 0; r < 4; ++r) tmp[nt][r] = xr[nt][r];
        __syncthreads();
        for (int nt = 0; nt < 2; ++nt) {
            int n = strip0 + nt * 16 + l15;
            for (int r = 0; r < 4; ++r) xf[lg * 4 + r][n] = tmp[nt][r];
        }
    }
    __syncthreads();

    {   // depth head: hid = relu(x @ dw1 + db1)
        int c = tid & 255;
        int r0 = (tid >> 8) * 4;
        float a4[4] = {0.f, 0.f, 0.f, 0.f};
        for (int k = 0; k < 512; ++k) {
            float w = dw1[(size_t)k * 256 + c];
            for (int j = 0; j < 4; ++j) a4[j] += xf[r0 + j][k] * w;
        }
        float bv = db1[c];
        for (int j = 0; j < 4; ++j) {
            float hv = a4[j] + bv;
            hid[r0 + j][c] = hv > 0.f ? hv : 0.f;
        }
    }
    __syncthreads();
    if (tid < 16) {
        float s = db2[0];
        for (int c = 0; c < 256; ++c) s += hid[tid][c] * dw2[c];
        out[(size_t)(b0 + tid) * 515] = s;
    }
    __syncthreads();
    {   // emotion head
        int c = tid & 255;
        int r0 = (tid >> 8) * 4;
        float a4[4] = {0.f, 0.f, 0.f, 0.f};
        for (int k = 0; k < 512; ++k) {
            float w = ew1[(size_t)k * 256 + c];
            for (int j = 0; j < 4; ++j) a4[j] += xf[r0 + j][k] * w;
        }
        float bv = eb1[c];
        for (int j = 0; j < 4; ++j) {
            float hv = a4[j] + bv;
            hid[r0 + j][c] = hv > 0.f ? hv : 0.f;
        }
    }
    __syncthreads();
    if (tid < 16) {
        float s1 = eb2[0], s2 = eb2[1];
        for (int c = 0; c < 256; ++c) {
            float hv = hid[tid][c];
            s1 += hv * ew2[2 * c];
            s2 += hv * ew2[2 * c + 1];
        }
        out[(size_t)(b0 + tid) * 515 + 1] = s1;
        out[(size_t)(b0 + tid) * 515 + 2] = s2;
    }
    for (int e = tid; e < 16 * 512; e += 1024) {
        int r = e >> 9, k = e & 511;
        out[(size_t)(b0 + r) * 515 + 3 + k] = xf[r][k];
    }
}

extern "C" void kernel_launch(void* const* d_in, const int* in_sizes, int n_in,
                              void* d_out, int out_size, void* d_ws, size_t ws_size,
                              hipStream_t stream) {
    const float* x0  = (const float*)d_in[0];
    const float* tw1 = (const float*)d_in[1];
    const float* tb1 = (const float*)d_in[2];
    const float* tw2 = (const float*)d_in[3];
    const float* tb2 = (const float*)d_in[4];
    const float* nw1 = (const float*)d_in[5];
    const float* nb1 = (const float*)d_in[6];
    const float* nw2 = (const float*)d_in[7];
    const float* nb2 = (const float*)d_in[8];
    const float* dw1 = (const float*)d_in[9];
    const float* db1 = (const float*)d_in[10];
    const float* dw2 = (const float*)d_in[11];
    const float* db2 = (const float*)d_in[12];
    const float* ew1 = (const float*)d_in[13];
    const float* eb1 = (const float*)d_in[14];
    const float* ew2 = (const float*)d_in[15];
    const float* eb2 = (const float*)d_in[16];
    float* out = (float*)d_out;

    float* ws    = (float*)d_ws;
    float* sfeat = ws;                   // 512000 f
    float* te    = sfeat + 512000;       // 512000 f
    float* tep   = te + 512000;          // 512000 f
    float* Asv   = tep + 512000;         // 1024 f each
    float* Bcv   = Asv + 1024;
    float* Dcv   = Bcv + 1024;
    short* w1h   = (short*)(Dcv + 1024); // 4 planes x 262144 shorts
    short* w1l   = w1h + 262144;
    short* w2h   = w1l + 262144;
    short* w2l   = w2h + 262144;

    hipLaunchKernelGGL(scalars_kernel, dim3(1), dim3(64), 0, stream, Asv, Bcv, Dcv);
    hipLaunchKernelGGL(feats_kernel, dim3(2000), dim3(256), 0, stream, tw1, tb1, sfeat);
    hipLaunchKernelGGL(gemm_kernel, dim3(16, 8), dim3(256), 0, stream, sfeat, tw2, tb2, te, 1000);
    hipLaunchKernelGGL(gemm_kernel, dim3(16, 8), dim3(256), 0, stream, te, nw1 + 512 * 512, nb1, tep, 1000);
    hipLaunchKernelGGL(tpack_kernel, dim3(1024), dim3(256), 0, stream, nw1, w1h, w1l);
    hipLaunchKernelGGL(tpack_kernel, dim3(1024), dim3(256), 0, stream, nw2, w2h, w2l);
    hipLaunchKernelGGL(diffusion_main, dim3(16), dim3(1024), 0, stream,
                       x0, w1h, w1l, w2h, w2l, tep, nb2,
                       Asv, Bcv, Dcv,
                       dw1, db1, dw2, db2, ew1, eb1, ew2, eb2, out);
}

// Round 5
// 38164.285 us; speedup vs baseline: 3.8910x; 1.2992x over previous
//
#include <hip/hip_runtime.h>
#include <stdint.h>
#include <math.h>

#define T_STEPS 1000

typedef __attribute__((ext_vector_type(4))) float f32x4;
typedef __attribute__((ext_vector_type(8))) _Float16 f16x8;
typedef __attribute__((ext_vector_type(4))) int i32x4;

#define C_2M11 4.8828125e-4f         // 2^-11
#define C_2M22 2.384185791015625e-7f // 2^-22
#define F16_MINNORM 6.103515625e-05f

__device__ __forceinline__ void split2h(float v, _Float16& hi, _Float16& lo) {
    float av = fabsf(v);
    _Float16 h = (av < F16_MINNORM) ? (_Float16)0.0f : (_Float16)v;
    float r = v - (float)h;
    hi = h;
    lo = (_Float16)(r * 2048.0f);
}
__device__ __forceinline__ short f2s(_Float16 h) {
    union { _Float16 h; short s; } u; u.h = h; return u.s;
}

#define MFMAH(a, b, c) __builtin_amdgcn_mfma_f32_16x16x32_f16((a), (b), (c), 0, 0, 0)

// ---------------- coefficients ----------------
__global__ void scalars_kernel(float* As, float* Bc, float* Dc) {
    if (threadIdx.x == 0 && blockIdx.x == 0) {
        float acp = 1.0f, ac_prev = 1.0f;
        for (int t = 0; t < T_STEPS; ++t) {
            float beta = (float)(1.0e-4 + (double)t * ((0.02 - 1.0e-4) / 999.0));
            acp = acp * (1.0f - beta);
            int i = (T_STEPS - 1) - t;
            As[i] = sqrtf(acp);
            Bc[i] = sqrtf(1.0f - acp);
            Dc[i] = sqrtf(1.0f - ac_prev) + sqrtf(beta);
            ac_prev = acp;
        }
    }
}

__global__ void zero_kernel(int* p, int n) {
    int i = blockIdx.x * 64 + threadIdx.x;
    if (i < n) p[i] = 0;
}

// ---------------- silu time features ----------------
__global__ __launch_bounds__(256) void feats_kernel(const float* tw1, const float* tb1, float* s) {
    int idx = blockIdx.x * 256 + threadIdx.x;
    if (idx < T_STEPS * 512) {
        int t = idx >> 9, m = idx & 511;
        float a = (float)t * tw1[m] + tb1[m];
        s[idx] = a / (1.0f + expf(-a));
    }
}

// ---------------- fp32 GEMM: C[M,512] = A[M,512] @ B[512,512] + bias ----------------
__global__ __launch_bounds__(256) void gemm_kernel(const float* A, const float* B,
                                                   const float* bias, float* C, int M) {
    __shared__ float Asm[16][68];
    __shared__ float Bsm[16][68];
    int tx = threadIdx.x & 15, ty = threadIdx.x >> 4;
    int m0 = blockIdx.x * 64, n0 = blockIdx.y * 64;
    float acc[4][4] = {};
    for (int k0 = 0; k0 < 512; k0 += 16) {
        for (int l = 0; l < 4; ++l) {
            int e = threadIdx.x + l * 256;
            int mm = e >> 4, kk = e & 15;
            Asm[kk][mm] = (m0 + mm < M) ? A[(size_t)(m0 + mm) * 512 + k0 + kk] : 0.0f;
            int nn = e & 63, kk2 = e >> 6;
            Bsm[kk2][nn] = B[(size_t)(k0 + kk2) * 512 + n0 + nn];
        }
        __syncthreads();
        for (int kk = 0; kk < 16; ++kk) {
            float a[4], b[4];
            for (int i = 0; i < 4; ++i) a[i] = Asm[kk][ty * 4 + i];
            for (int j = 0; j < 4; ++j) b[j] = Bsm[kk][tx * 4 + j];
            for (int i = 0; i < 4; ++i)
                for (int j = 0; j < 4; ++j) acc[i][j] += a[i] * b[j];
        }
        __syncthreads();
    }
    for (int i = 0; i < 4; ++i) {
        int m = m0 + ty * 4 + i;
        if (m < M)
            for (int j = 0; j < 4; ++j) {
                int n = n0 + tx * 4 + j;
                C[(size_t)m * 512 + n] = acc[i][j] + bias[n];
            }
    }
}

// ---------------- pack weight fragment-order + 2-limb fp16 split ----------------
// chunk = (n>>4)*16 + (k>>5); inchunk = (n&15)*32 + (k&31)
__global__ __launch_bounds__(256) void tpack_kernel(const float* w, short* ph, short* pl) {
    int p = blockIdx.x * 256 + threadIdx.x;
    if (p < 512 * 512) {
        int chunk = p >> 9, inch = p & 511;
        int n = (chunk >> 4) * 16 + (inch >> 5);
        int k = (chunk & 15) * 32 + (inch & 31);
        float v = w[(size_t)k * 512 + n];
        _Float16 hi, lo;
        split2h(v, hi, lo);
        ph[p] = f2s(hi);
        pl[p] = f2s(lo);
    }
}

// device-scope group barrier (16 blocks), monotone target
__device__ __forceinline__ void group_barrier(int* bar, int target) {
    __threadfence();
    if (threadIdx.x == 0)
        __hip_atomic_fetch_add(bar, 1, __ATOMIC_RELEASE, __HIP_MEMORY_SCOPE_AGENT);
    int spins = 0;
    while (__hip_atomic_load(bar, __ATOMIC_ACQUIRE, __HIP_MEMORY_SCOPE_AGENT) < target) {
        __builtin_amdgcn_s_sleep(2);
        if (++spins > (1 << 15)) break;  // hang guard; never triggers when co-resident
    }
    __threadfence();
}

// ---------------- main loop: 256 blocks x 64 threads, weights resident per CU ----------------
__global__ __launch_bounds__(64, 1) void diffusion_main(
    const float* x0,
    const short* w1h_, const short* w1l_,
    const short* w2h_, const short* w2l_,
    short* xgh, short* xgl, short* hgh, short* hgl,
    float* hid_d, float* hid_e, int* ctr,
    const float* tep, const float* nb2,
    const float* As, const float* Bc, const float* Dc,
    const float* dw1, const float* db1, const float* dw2, const float* db2,
    const float* ew1, const float* eb1, const float* ew2, const float* eb2,
    float* out) {

    __shared__ short wlds[32768];  // [0,16384): W1hi slice, [16384,32768): W2hi slice

    const int bid = blockIdx.x;
    const int rg = ((bid & 7) << 1) | (bid >> 7);  // row-group, co-located per XCD
    const int cg = (bid >> 3) & 15;                // col-slice
    const int lane = threadIdx.x;
    const int l15 = lane & 15, lg = lane >> 4;
    const int aoff = l15 * 32 + lg * 8;            // fragment lane offset within a chunk
    const int b0 = rg * 16;
    int* bar = ctr + rg * 32;

    const short* w1hS = w1h_ + (size_t)cg * 16384;
    const short* w1lS = w1l_ + (size_t)cg * 16384;
    const short* w2hS = w2h_ + (size_t)cg * 16384;
    const short* w2lS = w2l_ + (size_t)cg * 16384;

    // fill LDS with hi-limb weight slices (one-time)
    {
        const i32x4* s1 = (const i32x4*)w1hS;
        const i32x4* s2 = (const i32x4*)w2hS;
        i32x4* d = (i32x4*)wlds;
        for (int e = lane; e < 2048; e += 64) d[e] = s1[e];
        for (int e = lane; e < 2048; e += 64) d[2048 + e] = s2[e];
    }
    // lo-limb weights resident in registers (one-time)
    f16x8 w1lo[16][2], w2lo[16][2];
#pragma unroll
    for (int kb = 0; kb < 16; ++kb)
#pragma unroll
        for (int nt = 0; nt < 2; ++nt) {
            w1lo[kb][nt] = *(const f16x8*)(w1lS + (nt * 16 + kb) * 512 + aoff);
            w2lo[kb][nt] = *(const f16x8*)(w2lS + (nt * 16 + kb) * 512 + aoff);
        }

    short* xghR = xgh + rg * 8192;
    short* xglR = xgl + rg * 8192;
    short* hghR = hgh + rg * 8192;
    short* hglR = hgl + rg * 8192;

    // init x slice (C/D layout in regs) + publish packed chunk cg
    float xr[2][4], nb2r[2];
    for (int nt = 0; nt < 2; ++nt) {
        int n = cg * 32 + nt * 16 + l15;
        nb2r[nt] = nb2[n];
        for (int r = 0; r < 4; ++r) {
            float v = x0[(size_t)(b0 + lg * 4 + r) * 512 + n];
            xr[nt][r] = v;
            _Float16 hi, lo;
            split2h(v, hi, lo);
            int o = cg * 512 + (lg * 4 + r) * 32 + nt * 16 + l15;
            xghR[o] = f2s(hi);
            xglR[o] = f2s(lo);
        }
    }
    __syncthreads();
    int seq = 1;
    group_barrier(bar, 16 * seq); ++seq;

#pragma unroll 1
    for (int i = 0; i < T_STEPS; ++i) {
        const int t = (T_STEPS - 1) - i;
        float tep_r[2];
        tep_r[0] = tep[(size_t)t * 512 + cg * 32 + l15];
        tep_r[1] = tep[(size_t)t * 512 + cg * 32 + 16 + l15];
        const float a_s = As[i], bc = Bc[i], dc = Dc[i];

        // ---- GEMM1: h_slice = relu(x @ W1slice + tep) ----
        f32x4 a0[2], a1[2], a2[2];
#pragma unroll
        for (int nt = 0; nt < 2; ++nt) {
            a0[nt] = (f32x4){0.f, 0.f, 0.f, 0.f};
            a1[nt] = (f32x4){0.f, 0.f, 0.f, 0.f};
            a2[nt] = (f32x4){0.f, 0.f, 0.f, 0.f};
        }
        {
            f16x8 pah[8], pal[8], qah[8], qal[8];
#pragma unroll
            for (int kb = 0; kb < 8; ++kb) {
                pah[kb] = *(const f16x8*)(xghR + kb * 512 + aoff);
                pal[kb] = *(const f16x8*)(xglR + kb * 512 + aoff);
            }
#pragma unroll
            for (int kb = 0; kb < 8; ++kb) {
                qah[kb] = *(const f16x8*)(xghR + (8 + kb) * 512 + aoff);
                qal[kb] = *(const f16x8*)(xglR + (8 + kb) * 512 + aoff);
            }
#pragma unroll
            for (int kb = 0; kb < 16; ++kb) {
                f16x8 ah = (kb < 8) ? pah[kb & 7] : qah[kb & 7];
                f16x8 al = (kb < 8) ? pal[kb & 7] : qal[kb & 7];
#pragma unroll
                for (int nt = 0; nt < 2; ++nt) {
                    f16x8 bh = *(const f16x8*)(&wlds[(nt * 16 + kb) * 512 + aoff]);
                    f16x8 bl = w1lo[kb][nt];
                    a0[nt] = MFMAH(ah, bh, a0[nt]);
                    a1[nt] = MFMAH(ah, bl, a1[nt]);
                    a1[nt] = MFMAH(al, bh, a1[nt]);
                    a2[nt] = MFMAH(al, bl, a2[nt]);
                }
            }
        }
#pragma unroll
        for (int nt = 0; nt < 2; ++nt)
#pragma unroll
            for (int r = 0; r < 4; ++r) {
                float hv = a0[nt][r] + a1[nt][r] * C_2M11 + a2[nt][r] * C_2M22 + tep_r[nt];
                hv = hv > 0.f ? hv : 0.f;
                _Float16 hi, lo;
                split2h(hv, hi, lo);
                int o = cg * 512 + (lg * 4 + r) * 32 + nt * 16 + l15;
                hghR[o] = f2s(hi);
                hglR[o] = f2s(lo);
            }
        group_barrier(bar, 16 * seq); ++seq;

        // ---- GEMM2: eps_slice = h @ W2slice + nb2; x update ----
#pragma unroll
        for (int nt = 0; nt < 2; ++nt) {
            a0[nt] = (f32x4){0.f, 0.f, 0.f, 0.f};
            a1[nt] = (f32x4){0.f, 0.f, 0.f, 0.f};
            a2[nt] = (f32x4){0.f, 0.f, 0.f, 0.f};
        }
        {
            f16x8 pah[8], pal[8], qah[8], qal[8];
#pragma unroll
            for (int kb = 0; kb < 8; ++kb) {
                pah[kb] = *(const f16x8*)(hghR + kb * 512 + aoff);
                pal[kb] = *(const f16x8*)(hglR + kb * 512 + aoff);
            }
#pragma unroll
            for (int kb = 0; kb < 8; ++kb) {
                qah[kb] = *(const f16x8*)(hghR + (8 + kb) * 512 + aoff);
                qal[kb] = *(const f16x8*)(hglR + (8 + kb) * 512 + aoff);
            }
#pragma unroll
            for (int kb = 0; kb < 16; ++kb) {
                f16x8 ah = (kb < 8) ? pah[kb & 7] : qah[kb & 7];
                f16x8 al = (kb < 8) ? pal[kb & 7] : qal[kb & 7];
#pragma unroll
                for (int nt = 0; nt < 2; ++nt) {
                    f16x8 bh = *(const f16x8*)(&wlds[16384 + (nt * 16 + kb) * 512 + aoff]);
                    f16x8 bl = w2lo[kb][nt];
                    a0[nt] = MFMAH(ah, bh, a0[nt]);
                    a1[nt] = MFMAH(ah, bl, a1[nt]);
                    a1[nt] = MFMAH(al, bh, a1[nt]);
                    a2[nt] = MFMAH(al, bl, a2[nt]);
                }
            }
        }
#pragma unroll
        for (int nt = 0; nt < 2; ++nt)
#pragma unroll
            for (int r = 0; r < 4; ++r) {
                float eps = a0[nt][r] + a1[nt][r] * C_2M11 + a2[nt][r] * C_2M22 + nb2r[nt];
                float xv = (xr[nt][r] - bc * eps) / a_s + dc * eps;
                xv = fminf(fmaxf(xv, -1000.0f), 1000.0f);
                xr[nt][r] = xv;
                _Float16 hi, lo;
                split2h(xv, hi, lo);
                int o = cg * 512 + (lg * 4 + r) * 32 + nt * 16 + l15;
                xghR[o] = f2s(hi);
                xglR[o] = f2s(lo);
            }
        group_barrier(bar, 16 * seq); ++seq;
    }

    // ---- epilogue ----
    // x columns of output (exact fp32 from registers)
#pragma unroll
    for (int nt = 0; nt < 2; ++nt)
#pragma unroll
        for (int r = 0; r < 4; ++r)
            out[(size_t)(b0 + lg * 4 + r) * 515 + 3 + cg * 32 + nt * 16 + l15] = xr[nt][r];

    // head hidden slices: lane -> row m=l15, cols cbase..cbase+3
    {
        const int cbase = cg * 16 + lg * 4;
        float a4d[4] = {0.f, 0.f, 0.f, 0.f};
        float a4e[4] = {0.f, 0.f, 0.f, 0.f};
#pragma unroll 1
        for (int kb = 0; kb < 16; ++kb) {
#pragma unroll
            for (int d = 0; d < 4; ++d) {
                f16x8 xh8 = *(const f16x8*)(xghR + kb * 512 + l15 * 32 + d * 8);
                f16x8 xl8 = *(const f16x8*)(xglR + kb * 512 + l15 * 32 + d * 8);
#pragma unroll
                for (int jj = 0; jj < 8; ++jj) {
                    float xv = (float)xh8[jj] + (float)xl8[jj] * C_2M11;
                    int k = kb * 32 + d * 8 + jj;
                    f32x4 wd = *(const f32x4*)(dw1 + (size_t)k * 256 + cbase);
                    f32x4 we = *(const f32x4*)(ew1 + (size_t)k * 256 + cbase);
#pragma unroll
                    for (int j = 0; j < 4; ++j) {
                        a4d[j] += xv * wd[j];
                        a4e[j] += xv * we[j];
                    }
                }
            }
        }
#pragma unroll
        for (int j = 0; j < 4; ++j) {
            float hd = a4d[j] + db1[cbase + j];
            float he = a4e[j] + eb1[cbase + j];
            hid_d[rg * 4096 + l15 * 256 + cbase + j] = hd > 0.f ? hd : 0.f;
            hid_e[rg * 4096 + l15 * 256 + cbase + j] = he > 0.f ? he : 0.f;
        }
    }
    group_barrier(bar, 16 * seq); ++seq;

    if (cg == 0) {  // final head dots for this row-group
        float sd = 0.f, se1 = 0.f, se2 = 0.f;
        for (int cc = 0; cc < 64; ++cc) {
            int c = lg * 64 + cc;
            float hd = hid_d[rg * 4096 + l15 * 256 + c];
            float he = hid_e[rg * 4096 + l15 * 256 + c];
            sd += hd * dw2[c];
            se1 += he * ew2[2 * c];
            se2 += he * ew2[2 * c + 1];
        }
        sd += __shfl_xor(sd, 16); sd += __shfl_xor(sd, 32);
        se1 += __shfl_xor(se1, 16); se1 += __shfl_xor(se1, 32);
        se2 += __shfl_xor(se2, 16); se2 += __shfl_xor(se2, 32);
        if (lg == 0) {
            out[(size_t)(b0 + l15) * 515 + 0] = sd + db2[0];
            out[(size_t)(b0 + l15) * 515 + 1] = se1 + eb2[0];
            out[(size_t)(b0 + l15) * 515 + 2] = se2 + eb2[1];
        }
    }
}

extern "C" void kernel_launch(void* const* d_in, const int* in_sizes, int n_in,
                              void* d_out, int out_size, void* d_ws, size_t ws_size,
                              hipStream_t stream) {
    const float* x0  = (const float*)d_in[0];
    const float* tw1 = (const float*)d_in[1];
    const float* tb1 = (const float*)d_in[2];
    const float* tw2 = (const float*)d_in[3];
    const float* tb2 = (const float*)d_in[4];
    const float* nw1 = (const float*)d_in[5];
    const float* nb1 = (const float*)d_in[6];
    const float* nw2 = (const float*)d_in[7];
    const float* nb2 = (const float*)d_in[8];
    const float* dw1 = (const float*)d_in[9];
    const float* db1 = (const float*)d_in[10];
    const float* dw2 = (const float*)d_in[11];
    const float* db2 = (const float*)d_in[12];
    const float* ew1 = (const float*)d_in[13];
    const float* eb1 = (const float*)d_in[14];
    const float* ew2 = (const float*)d_in[15];
    const float* eb2 = (const float*)d_in[16];
    float* out = (float*)d_out;

    float* ws    = (float*)d_ws;
    float* sfeat = ws;                   // 512000 f
    float* te    = sfeat + 512000;       // 512000 f
    float* tep   = te + 512000;          // 512000 f
    float* Asv   = tep + 512000;         // 1024 f each
    float* Bcv   = Asv + 1024;
    float* Dcv   = Bcv + 1024;
    short* w1h   = (short*)(Dcv + 1024); // 4 planes x 262144 shorts
    short* w1l   = w1h + 262144;
    short* w2h   = w1l + 262144;
    short* w2l   = w2h + 262144;
    short* xghp  = w2l + 262144;         // 4 exchange planes x 131072 shorts
    short* xglp  = xghp + 131072;
    short* hghp  = xglp + 131072;
    short* hglp  = hghp + 131072;
    float* hid_d = (float*)(hglp + 131072); // 65536 f each
    float* hid_e = hid_d + 65536;
    int*   ctr   = (int*)(hid_e + 65536);   // 512 ints

    hipLaunchKernelGGL(scalars_kernel, dim3(1), dim3(64), 0, stream, Asv, Bcv, Dcv);
    hipLaunchKernelGGL(zero_kernel, dim3(8), dim3(64), 0, stream, ctr, 512);
    hipLaunchKernelGGL(feats_kernel, dim3(2000), dim3(256), 0, stream, tw1, tb1, sfeat);
    hipLaunchKernelGGL(gemm_kernel, dim3(16, 8), dim3(256), 0, stream, sfeat, tw2, tb2, te, 1000);
    hipLaunchKernelGGL(gemm_kernel, dim3(16, 8), dim3(256), 0, stream, te, nw1 + 512 * 512, nb1, tep, 1000);
    hipLaunchKernelGGL(tpack_kernel, dim3(1024), dim3(256), 0, stream, nw1, w1h, w1l);
    hipLaunchKernelGGL(tpack_kernel, dim3(1024), dim3(256), 0, stream, nw2, w2h, w2l);
    hipLaunchKernelGGL(diffusion_main, dim3(256), dim3(64), 0, stream,
                       x0, w1h, w1l, w2h, w2l,
                       xghp, xglp, hghp, hglp, hid_d, hid_e, ctr,
                       tep, nb2, Asv, Bcv, Dcv,
                       dw1, db1, dw2, db2, ew1, eb1, ew2, eb2, out);
}

// Round 6
// 12615.893 us; speedup vs baseline: 11.7706x; 3.0251x over previous
//
#include <hip/hip_runtime.h>
#include <stdint.h>
#include <math.h>

#define T_STEPS 1000

typedef __attribute__((ext_vector_type(4))) float f32x4;
typedef __attribute__((ext_vector_type(8))) _Float16 f16x8;
typedef __attribute__((ext_vector_type(4))) int i32x4;

#define C_2M11 4.8828125e-4f         // 2^-11
#define C_2M22 2.384185791015625e-7f // 2^-22
#define F16_MINNORM 6.103515625e-05f

#define VMCNT0() asm volatile("s_waitcnt vmcnt(0)" ::: "memory")
#define DEP8(x)  asm volatile("" : "+v"(x))

__device__ __forceinline__ void split2h(float v, _Float16& hi, _Float16& lo) {
    float av = fabsf(v);
    _Float16 h = (av < F16_MINNORM) ? (_Float16)0.0f : (_Float16)v;
    float r = v - (float)h;
    hi = h;
    lo = (_Float16)(r * 2048.0f);
}
__device__ __forceinline__ short f2s(_Float16 h) {
    union { _Float16 h; short s; } u; u.h = h; return u.s;
}

// ---- device-coherent (coherence-point) memory ops: bypass L1+local-L2 ----
__device__ __forceinline__ f16x8 coh_load8h(const short* p) {
    union { i32x4 i; f16x8 h; } u;
    asm volatile("global_load_dwordx4 %0, %1, off sc0 sc1" : "=v"(u.i) : "v"(p) : "memory");
    return u.h;
}
__device__ __forceinline__ f32x4 coh_load4f(const float* p) {
    f32x4 v;
    asm volatile("global_load_dwordx4 %0, %1, off sc0 sc1" : "=v"(v) : "v"(p) : "memory");
    return v;
}
__device__ __forceinline__ int coh_load_int_wait(const int* p) {
    int v;
    asm volatile("global_load_dword %0, %1, off sc0 sc1\n\ts_waitcnt vmcnt(0)"
                 : "=v"(v) : "v"(p) : "memory");
    return v;
}
__device__ __forceinline__ void coh_store_s(short* p, short v) {
    int iv = (int)(unsigned short)v;
    asm volatile("global_store_short %0, %1, off sc0 sc1" :: "v"(p), "v"(iv) : "memory");
}
__device__ __forceinline__ void coh_store4f(float* p, f32x4 v) {
    asm volatile("global_store_dwordx4 %0, %1, off sc0 sc1" :: "v"(p), "v"(v) : "memory");
}
__device__ __forceinline__ void coh_store_i(int* p, int v) {
    asm volatile("global_store_dword %0, %1, off sc0 sc1" :: "v"(p), "v"(v) : "memory");
}
__device__ __forceinline__ void coh_atomic_inc(int* p) {
    int one = 1;
    asm volatile("global_atomic_add %0, %1, off sc1" :: "v"(p), "v"(one) : "memory");
}

// fence-free group barrier: stores already drained via VMCNT0; counter lives at
// the coherence point (sc1 atomic); spin reads the coherence point (sc0 sc1).
__device__ __forceinline__ void group_barrier(int* bar, int target) {
    VMCNT0();
    if (threadIdx.x == 0) coh_atomic_inc(bar);
    int spins = 0;
    while (coh_load_int_wait(bar) < target) {
        if (++spins > (1 << 17)) break;  // hang guard; co-residency guaranteed (256 blocks / 256 CUs)
    }
}

#define MFMAH(a, b, c) __builtin_amdgcn_mfma_f32_16x16x32_f16((a), (b), (c), 0, 0, 0)

// ---------------- coefficients ----------------
__global__ void scalars_kernel(float* As, float* Bc, float* Dc) {
    if (threadIdx.x == 0 && blockIdx.x == 0) {
        float acp = 1.0f, ac_prev = 1.0f;
        for (int t = 0; t < T_STEPS; ++t) {
            float beta = (float)(1.0e-4 + (double)t * ((0.02 - 1.0e-4) / 999.0));
            acp = acp * (1.0f - beta);
            int i = (T_STEPS - 1) - t;
            As[i] = sqrtf(acp);
            Bc[i] = sqrtf(1.0f - acp);
            Dc[i] = sqrtf(1.0f - ac_prev) + sqrtf(beta);
            ac_prev = acp;
        }
    }
}

__global__ void zero_kernel(int* p, int n) {
    int i = blockIdx.x * 64 + threadIdx.x;
    if (i < n) coh_store_i(p + i, 0);   // write-through so the coherence point holds 0
}

// ---------------- silu time features ----------------
__global__ __launch_bounds__(256) void feats_kernel(const float* tw1, const float* tb1, float* s) {
    int idx = blockIdx.x * 256 + threadIdx.x;
    if (idx < T_STEPS * 512) {
        int t = idx >> 9, m = idx & 511;
        float a = (float)t * tw1[m] + tb1[m];
        s[idx] = a / (1.0f + expf(-a));
    }
}

// ---------------- fp32 GEMM: C[M,512] = A[M,512] @ B[512,512] + bias ----------------
__global__ __launch_bounds__(256) void gemm_kernel(const float* A, const float* B,
                                                   const float* bias, float* C, int M) {
    __shared__ float Asm[16][68];
    __shared__ float Bsm[16][68];
    int tx = threadIdx.x & 15, ty = threadIdx.x >> 4;
    int m0 = blockIdx.x * 64, n0 = blockIdx.y * 64;
    float acc[4][4] = {};
    for (int k0 = 0; k0 < 512; k0 += 16) {
        for (int l = 0; l < 4; ++l) {
            int e = threadIdx.x + l * 256;
            int mm = e >> 4, kk = e & 15;
            Asm[kk][mm] = (m0 + mm < M) ? A[(size_t)(m0 + mm) * 512 + k0 + kk] : 0.0f;
            int nn = e & 63, kk2 = e >> 6;
            Bsm[kk2][nn] = B[(size_t)(k0 + kk2) * 512 + n0 + nn];
        }
        __syncthreads();
        for (int kk = 0; kk < 16; ++kk) {
            float a[4], b[4];
            for (int i = 0; i < 4; ++i) a[i] = Asm[kk][ty * 4 + i];
            for (int j = 0; j < 4; ++j) b[j] = Bsm[kk][tx * 4 + j];
            for (int i = 0; i < 4; ++i)
                for (int j = 0; j < 4; ++j) acc[i][j] += a[i] * b[j];
        }
        __syncthreads();
    }
    for (int i = 0; i < 4; ++i) {
        int m = m0 + ty * 4 + i;
        if (m < M)
            for (int j = 0; j < 4; ++j) {
                int n = n0 + tx * 4 + j;
                C[(size_t)m * 512 + n] = acc[i][j] + bias[n];
            }
    }
}

// ---------------- pack weight fragment-order + 2-limb fp16 split ----------------
__global__ __launch_bounds__(256) void tpack_kernel(const float* w, short* ph, short* pl) {
    int p = blockIdx.x * 256 + threadIdx.x;
    if (p < 512 * 512) {
        int chunk = p >> 9, inch = p & 511;
        int n = (chunk >> 4) * 16 + (inch >> 5);
        int k = (chunk & 15) * 32 + (inch & 31);
        float v = w[(size_t)k * 512 + n];
        _Float16 hi, lo;
        split2h(v, hi, lo);
        ph[p] = f2s(hi);
        pl[p] = f2s(lo);
    }
}

// ---------------- main loop: 256 blocks x 64 threads ----------------
__global__ __launch_bounds__(64, 1) void diffusion_main(
    const float* x0,
    const short* w1h_, const short* w1l_,
    const short* w2h_, const short* w2l_,
    short* xgh, short* xgl, short* hgh, short* hgl,
    float* hid_d, float* hid_e, int* ctr,
    const float* tep, const float* nb2,
    const float* As, const float* Bc, const float* Dc,
    const float* dw1, const float* db1, const float* dw2, const float* db2,
    const float* ew1, const float* eb1, const float* ew2, const float* eb2,
    float* out) {

    __shared__ short wlds[32768];  // [0,16384): W1hi slice, [16384,32768): W2hi slice

    const int bid = blockIdx.x;
    const int rg = ((bid & 7) << 1) | (bid >> 7);
    const int cg = (bid >> 3) & 15;
    const int lane = threadIdx.x;
    const int l15 = lane & 15, lg = lane >> 4;
    const int aoff = l15 * 32 + lg * 8;
    const int b0 = rg * 16;
    int* bar = ctr + rg * 32;

    const short* w1hS = w1h_ + (size_t)cg * 16384;
    const short* w1lS = w1l_ + (size_t)cg * 16384;
    const short* w2hS = w2h_ + (size_t)cg * 16384;
    const short* w2lS = w2l_ + (size_t)cg * 16384;

    // one-time: hi-limb weight slices into LDS (plain cached loads)
    {
        const i32x4* s1 = (const i32x4*)w1hS;
        const i32x4* s2 = (const i32x4*)w2hS;
        i32x4* d = (i32x4*)wlds;
        for (int e = lane; e < 2048; e += 64) d[e] = s1[e];
        for (int e = lane; e < 2048; e += 64) d[2048 + e] = s2[e];
    }
    __syncthreads();

    short* xghR = xgh + rg * 8192;
    short* xglR = xgl + rg * 8192;
    short* hghR = hgh + rg * 8192;
    short* hglR = hgl + rg * 8192;

    // init x slice + publish (coherence-point stores)
    float xr[2][4], nb2r[2];
    for (int nt = 0; nt < 2; ++nt) {
        int n = cg * 32 + nt * 16 + l15;
        nb2r[nt] = nb2[n];
        for (int r = 0; r < 4; ++r) {
            float v = x0[(size_t)(b0 + lg * 4 + r) * 512 + n];
            xr[nt][r] = v;
            _Float16 hi, lo;
            split2h(v, hi, lo);
            int o = cg * 512 + (lg * 4 + r) * 32 + nt * 16 + l15;
            coh_store_s(xghR + o, f2s(hi));
            coh_store_s(xglR + o, f2s(lo));
        }
    }
    int seq = 1;
    group_barrier(bar, 16 * seq); ++seq;

#pragma unroll 1
    for (int i = 0; i < T_STEPS; ++i) {
        const int t = (T_STEPS - 1) - i;
        float tep_r[2];
        tep_r[0] = tep[(size_t)t * 512 + cg * 32 + l15];
        tep_r[1] = tep[(size_t)t * 512 + cg * 32 + 16 + l15];
        const float a_s = As[i], bc = Bc[i], dc = Dc[i];

        // ---- GEMM1: h_slice = relu(x @ W1slice + tep) ----
        f32x4 a0[2], a1[2], a2[2];
#pragma unroll
        for (int nt = 0; nt < 2; ++nt) {
            a0[nt] = (f32x4){0.f, 0.f, 0.f, 0.f};
            a1[nt] = (f32x4){0.f, 0.f, 0.f, 0.f};
            a2[nt] = (f32x4){0.f, 0.f, 0.f, 0.f};
        }
        {
            f16x8 xa_h[16], xa_l[16];
#pragma unroll
            for (int kb = 0; kb < 16; ++kb) {
                xa_h[kb] = coh_load8h(xghR + kb * 512 + aoff);
                xa_l[kb] = coh_load8h(xglR + kb * 512 + aoff);
            }
            VMCNT0();
#pragma unroll
            for (int kb = 0; kb < 16; ++kb) { DEP8(xa_h[kb]); DEP8(xa_l[kb]); }
#pragma unroll
            for (int kb = 0; kb < 16; ++kb) {
                f16x8 ah = xa_h[kb], al = xa_l[kb];
#pragma unroll
                for (int nt = 0; nt < 2; ++nt) {
                    f16x8 bh = *(const f16x8*)(&wlds[(nt * 16 + kb) * 512 + aoff]);
                    f16x8 bl = *(const f16x8*)(w1lS + (nt * 16 + kb) * 512 + aoff);
                    a0[nt] = MFMAH(ah, bh, a0[nt]);
                    a1[nt] = MFMAH(ah, bl, a1[nt]);
                    a1[nt] = MFMAH(al, bh, a1[nt]);
                    a2[nt] = MFMAH(al, bl, a2[nt]);
                }
            }
        }
#pragma unroll
        for (int nt = 0; nt < 2; ++nt)
#pragma unroll
            for (int r = 0; r < 4; ++r) {
                float hv = a0[nt][r] + a1[nt][r] * C_2M11 + a2[nt][r] * C_2M22 + tep_r[nt];
                hv = hv > 0.f ? hv : 0.f;
                _Float16 hi, lo;
                split2h(hv, hi, lo);
                int o = cg * 512 + (lg * 4 + r) * 32 + nt * 16 + l15;
                coh_store_s(hghR + o, f2s(hi));
                coh_store_s(hglR + o, f2s(lo));
            }
        group_barrier(bar, 16 * seq); ++seq;

        // ---- GEMM2: eps_slice = h @ W2slice + nb2; x update ----
#pragma unroll
        for (int nt = 0; nt < 2; ++nt) {
            a0[nt] = (f32x4){0.f, 0.f, 0.f, 0.f};
            a1[nt] = (f32x4){0.f, 0.f, 0.f, 0.f};
            a2[nt] = (f32x4){0.f, 0.f, 0.f, 0.f};
        }
        {
            f16x8 xa_h[16], xa_l[16];
#pragma unroll
            for (int kb = 0; kb < 16; ++kb) {
                xa_h[kb] = coh_load8h(hghR + kb * 512 + aoff);
                xa_l[kb] = coh_load8h(hglR + kb * 512 + aoff);
            }
            VMCNT0();
#pragma unroll
            for (int kb = 0; kb < 16; ++kb) { DEP8(xa_h[kb]); DEP8(xa_l[kb]); }
#pragma unroll
            for (int kb = 0; kb < 16; ++kb) {
                f16x8 ah = xa_h[kb], al = xa_l[kb];
#pragma unroll
                for (int nt = 0; nt < 2; ++nt) {
                    f16x8 bh = *(const f16x8*)(&wlds[16384 + (nt * 16 + kb) * 512 + aoff]);
                    f16x8 bl = *(const f16x8*)(w2lS + (nt * 16 + kb) * 512 + aoff);
                    a0[nt] = MFMAH(ah, bh, a0[nt]);
                    a1[nt] = MFMAH(ah, bl, a1[nt]);
                    a1[nt] = MFMAH(al, bh, a1[nt]);
                    a2[nt] = MFMAH(al, bl, a2[nt]);
                }
            }
        }
#pragma unroll
        for (int nt = 0; nt < 2; ++nt)
#pragma unroll
            for (int r = 0; r < 4; ++r) {
                float eps = a0[nt][r] + a1[nt][r] * C_2M11 + a2[nt][r] * C_2M22 + nb2r[nt];
                float xv = (xr[nt][r] - bc * eps) / a_s + dc * eps;
                xv = fminf(fmaxf(xv, -1000.0f), 1000.0f);
                xr[nt][r] = xv;
                _Float16 hi, lo;
                split2h(xv, hi, lo);
                int o = cg * 512 + (lg * 4 + r) * 32 + nt * 16 + l15;
                coh_store_s(xghR + o, f2s(hi));
                coh_store_s(xglR + o, f2s(lo));
            }
        group_barrier(bar, 16 * seq); ++seq;
    }

    // ---- epilogue ----
#pragma unroll
    for (int nt = 0; nt < 2; ++nt)
#pragma unroll
        for (int r = 0; r < 4; ++r)
            out[(size_t)(b0 + lg * 4 + r) * 515 + 3 + cg * 32 + nt * 16 + l15] = xr[nt][r];

    // head hidden slices: lane -> row m=l15, cols cbase..cbase+3
    {
        const int cbase = cg * 16 + lg * 4;
        float a4d[4] = {0.f, 0.f, 0.f, 0.f};
        float a4e[4] = {0.f, 0.f, 0.f, 0.f};
#pragma unroll 1
        for (int kb = 0; kb < 16; ++kb) {
            f16x8 xh8[4], xl8[4];
#pragma unroll
            for (int d = 0; d < 4; ++d) {
                xh8[d] = coh_load8h(xghR + kb * 512 + l15 * 32 + d * 8);
                xl8[d] = coh_load8h(xglR + kb * 512 + l15 * 32 + d * 8);
            }
            VMCNT0();
#pragma unroll
            for (int d = 0; d < 4; ++d) { DEP8(xh8[d]); DEP8(xl8[d]); }
#pragma unroll
            for (int d = 0; d < 4; ++d)
#pragma unroll
                for (int jj = 0; jj < 8; ++jj) {
                    float xv = (float)xh8[d][jj] + (float)xl8[d][jj] * C_2M11;
                    int k = kb * 32 + d * 8 + jj;
                    f32x4 wd = *(const f32x4*)(dw1 + (size_t)k * 256 + cbase);
                    f32x4 we = *(const f32x4*)(ew1 + (size_t)k * 256 + cbase);
#pragma unroll
                    for (int j = 0; j < 4; ++j) {
                        a4d[j] += xv * wd[j];
                        a4e[j] += xv * we[j];
                    }
                }
        }
        f32x4 hd, he;
#pragma unroll
        for (int j = 0; j < 4; ++j) {
            float hdv = a4d[j] + db1[cbase + j];
            float hev = a4e[j] + eb1[cbase + j];
            hd[j] = hdv > 0.f ? hdv : 0.f;
            he[j] = hev > 0.f ? hev : 0.f;
        }
        coh_store4f(hid_d + rg * 4096 + l15 * 256 + cbase, hd);
        coh_store4f(hid_e + rg * 4096 + l15 * 256 + cbase, he);
    }
    group_barrier(bar, 16 * seq); ++seq;

    if (cg == 0) {
        f32x4 hd4[16], he4[16];
#pragma unroll
        for (int q = 0; q < 16; ++q) {
            hd4[q] = coh_load4f(hid_d + rg * 4096 + l15 * 256 + lg * 64 + q * 4);
            he4[q] = coh_load4f(hid_e + rg * 4096 + l15 * 256 + lg * 64 + q * 4);
        }
        VMCNT0();
#pragma unroll
        for (int q = 0; q < 16; ++q) { DEP8(hd4[q]); DEP8(he4[q]); }
        float sd = 0.f, se1 = 0.f, se2 = 0.f;
#pragma unroll
        for (int q = 0; q < 16; ++q)
#pragma unroll
            for (int j = 0; j < 4; ++j) {
                int c = lg * 64 + q * 4 + j;
                sd += hd4[q][j] * dw2[c];
                se1 += he4[q][j] * ew2[2 * c];
                se2 += he4[q][j] * ew2[2 * c + 1];
            }
        sd += __shfl_xor(sd, 16); sd += __shfl_xor(sd, 32);
        se1 += __shfl_xor(se1, 16); se1 += __shfl_xor(se1, 32);
        se2 += __shfl_xor(se2, 16); se2 += __shfl_xor(se2, 32);
        if (lg == 0) {
            out[(size_t)(b0 + l15) * 515 + 0] = sd + db2[0];
            out[(size_t)(b0 + l15) * 515 + 1] = se1 + eb2[0];
            out[(size_t)(b0 + l15) * 515 + 2] = se2 + eb2[1];
        }
    }
}

extern "C" void kernel_launch(void* const* d_in, const int* in_sizes, int n_in,
                              void* d_out, int out_size, void* d_ws, size_t ws_size,
                              hipStream_t stream) {
    const float* x0  = (const float*)d_in[0];
    const float* tw1 = (const float*)d_in[1];
    const float* tb1 = (const float*)d_in[2];
    const float* tw2 = (const float*)d_in[3];
    const float* tb2 = (const float*)d_in[4];
    const float* nw1 = (const float*)d_in[5];
    const float* nb1 = (const float*)d_in[6];
    const float* nw2 = (const float*)d_in[7];
    const float* nb2 = (const float*)d_in[8];
    const float* dw1 = (const float*)d_in[9];
    const float* db1 = (const float*)d_in[10];
    const float* dw2 = (const float*)d_in[11];
    const float* db2 = (const float*)d_in[12];
    const float* ew1 = (const float*)d_in[13];
    const float* eb1 = (const float*)d_in[14];
    const float* ew2 = (const float*)d_in[15];
    const float* eb2 = (const float*)d_in[16];
    float* out = (float*)d_out;

    float* ws    = (float*)d_ws;
    float* sfeat = ws;                   // 512000 f
    float* te    = sfeat + 512000;       // 512000 f
    float* tep   = te + 512000;          // 512000 f
    float* Asv   = tep + 512000;         // 1024 f each
    float* Bcv   = Asv + 1024;
    float* Dcv   = Bcv + 1024;
    short* w1h   = (short*)(Dcv + 1024); // 4 planes x 262144 shorts
    short* w1l   = w1h + 262144;
    short* w2h   = w1l + 262144;
    short* w2l   = w2h + 262144;
    short* xghp  = w2l + 262144;         // 4 exchange planes x 131072 shorts
    short* xglp  = xghp + 131072;
    short* hghp  = xglp + 131072;
    short* hglp  = hghp + 131072;
    float* hid_d = (float*)(hglp + 131072); // 65536 f each
    float* hid_e = hid_d + 65536;
    int*   ctr   = (int*)(hid_e + 65536);   // 512 ints

    hipLaunchKernelGGL(scalars_kernel, dim3(1), dim3(64), 0, stream, Asv, Bcv, Dcv);
    hipLaunchKernelGGL(zero_kernel, dim3(8), dim3(64), 0, stream, ctr, 512);
    hipLaunchKernelGGL(feats_kernel, dim3(2000), dim3(256), 0, stream, tw1, tb1, sfeat);
    hipLaunchKernelGGL(gemm_kernel, dim3(16, 8), dim3(256), 0, stream, sfeat, tw2, tb2, te, 1000);
    hipLaunchKernelGGL(gemm_kernel, dim3(16, 8), dim3(256), 0, stream, te, nw1 + 512 * 512, nb1, tep, 1000);
    hipLaunchKernelGGL(tpack_kernel, dim3(1024), dim3(256), 0, stream, nw1, w1h, w1l);
    hipLaunchKernelGGL(tpack_kernel, dim3(1024), dim3(256), 0, stream, nw2, w2h, w2l);
    hipLaunchKernelGGL(diffusion_main, dim3(256), dim3(64), 0, stream,
                       x0, w1h, w1l, w2h, w2l,
                       xghp, xglp, hghp, hglp, hid_d, hid_e, ctr,
                       tep, nb2, Asv, Bcv, Dcv,
                       dw1, db1, dw2, db2, ew1, eb1, ew2, eb2, out);
}